// Round 8
// baseline (263.999 us; speedup 1.0000x reference)
//
#include <hip/hip_runtime.h>

#define BB 8
#define CC 64
#define HH 256
#define WW 256
#define KK 5

// 4x4 output block, read-base-relative: reads 8 rows x 3 aligned float4 at
// src + ir*SS; outputs land at src + (2+i)*SS + 4 + j. Taps e[2+j+kx].
template<int SS>
__device__ __forceinline__ void conv4x4_e12(const float* __restrict__ src,
                                            const float* __restrict__ wr,
                                            float bv, float a[4][4])
{
#pragma unroll
    for (int i = 0; i < 4; i++)
#pragma unroll
        for (int j = 0; j < 4; j++) a[i][j] = bv;
#pragma unroll
    for (int ir = 0; ir < 8; ir++) {
        const float* s = src + ir * SS;
        float4 A = *(const float4*)s;
        float4 B = *(const float4*)(s + 4);
        float4 C = *(const float4*)(s + 8);
        float e[12] = {A.x, A.y, A.z, A.w, B.x, B.y, B.z, B.w, C.x, C.y, C.z, C.w};
#pragma unroll
        for (int i = 0; i < 4; i++) {
            const int ky = ir - i;
            if (ky >= 0 && ky < 5) {
#pragma unroll
                for (int kx = 0; kx < 5; kx++) {
                    const float wv = wr[ky * 5 + kx];
#pragma unroll
                    for (int j = 0; j < 4; j++) a[i][j] += e[2 + j + kx] * wv;
                }
            }
        }
    }
}

// 2x4 variant: 6 rows x 3 float4; outputs at src + (2+i)*SS + 4 + j.
template<int SS>
__device__ __forceinline__ void conv2x4_e12(const float* __restrict__ src,
                                            const float* __restrict__ wr,
                                            float bv, float a[2][4])
{
#pragma unroll
    for (int i = 0; i < 2; i++)
#pragma unroll
        for (int j = 0; j < 4; j++) a[i][j] = bv;
#pragma unroll
    for (int ir = 0; ir < 6; ir++) {
        const float* s = src + ir * SS;
        float4 A = *(const float4*)s;
        float4 B = *(const float4*)(s + 4);
        float4 C = *(const float4*)(s + 8);
        float e[12] = {A.x, A.y, A.z, A.w, B.x, B.y, B.z, B.w, C.x, C.y, C.z, C.w};
#pragma unroll
        for (int i = 0; i < 2; i++) {
            const int ky = ir - i;
            if (ky >= 0 && ky < 5) {
#pragma unroll
                for (int kx = 0; kx < 5; kx++) {
                    const float wv = wr[ky * 5 + kx];
#pragma unroll
                    for (int j = 0; j < 4; j++) a[i][j] += e[2 + j + kx] * wv;
                }
            }
        }
    }
}

// ---------------------------------------------------------------------------
// Stage A: avgpool + 3x dwconv(128^2) + maxpool, HALF-plane per block.
// Block (plane, by): image rows R0..R0+63 (R0 = by*64). LDS 76x144 (43.8 KB,
// 3 blocks/CU): rows = image rows R0-6..R0+69, cols: image col j at 8+j
// (left pad 4 + halo 2 for fully-aligned b128 reads AND writes).
// 3 convs in place on a uniform 18x34 tile grid; writes outside the image
// predicated to zero; halo margins (6/4/2) keep garbage out of valid rows.
// Maxpool 2x2 of rows R0..R0+63 -> t2[plane][by*32..][64].
// ---------------------------------------------------------------------------
__global__ __launch_bounds__(512, 6) void k_a1(
    const float* __restrict__ x, const float* __restrict__ w1,
    const float* __restrict__ b1, float* __restrict__ t2)
{
    const int plane = blockIdx.x;          // b*64 + c
    const int c = plane & 63;
    const int by = blockIdx.y;             // 0,1
    const int R0 = by * 64;
    const int tid = threadIdx.x;

    __shared__ __align__(16) float sb[76 * 144];

    const float* xp = x + (size_t)plane * HH * WW;

    // fill: avgpool into buffer. 76 rows x 36 float4 items = 2736.
#pragma unroll
    for (int k = 0; k < 6; k++) {
        int i = tid + k * 512;
        if (i < 76 * 36) {
            int r = i / 36, q = i % 36;
            int pr = R0 - 6 + r;           // pooled row
            float4 v = make_float4(0.f, 0.f, 0.f, 0.f);
            if (q >= 2 && q <= 33 && (unsigned)pr < 128u) {
                int xc = 8 * q - 16;       // x col of first of 8
                const float* p0 = xp + (size_t)(2 * pr) * WW + xc;
                const float* p1 = p0 + WW;
                float4 a0 = *(const float4*)p0;
                float4 a1 = *(const float4*)(p0 + 4);
                float4 b0 = *(const float4*)p1;
                float4 b1v = *(const float4*)(p1 + 4);
                v.x = 0.25f * (a0.x + a0.y + b0.x + b0.y);
                v.y = 0.25f * (a0.z + a0.w + b0.z + b0.w);
                v.z = 0.25f * (a1.x + a1.y + b1v.x + b1v.y);
                v.w = 0.25f * (a1.z + a1.w + b1v.z + b1v.w);
            }
            *(float4*)&sb[r * 144 + 4 * q] = v;
        }
    }
    __syncthreads();

    // 3 convs in place; 612 tiles (18 rows x 34 cols), 2 passes over 512 thr.
#pragma unroll
    for (int cv = 0; cv < 3; cv++) {
        float wr[25];
#pragma unroll
        for (int k = 0; k < 25; k++) wr[k] = w1[cv * CC * 25 + c * 25 + k];
        const float bv = b1[cv * CC + c];

        float a0[4][4], a1[4][4];
        const int v0 = tid / 34, u0 = tid % 34;
        conv4x4_e12<144>(&sb[(4 * v0) * 144 + 4 * u0], wr, bv, a0);
        {
            const bool cok = (u0 >= 1 && u0 <= 32);
#pragma unroll
            for (int i = 0; i < 4; i++) {
                int gi = R0 - 4 + 4 * v0 + i;          // image row of write
                bool ok = cok && ((unsigned)gi < 128u);
#pragma unroll
                for (int j = 0; j < 4; j++) if (!ok) a0[i][j] = 0.f;
            }
        }
        const int t1i = tid + 512;
        const bool has2 = t1i < 612;
        const int v1 = t1i / 34, u1 = t1i % 34;
        if (has2) {
            conv4x4_e12<144>(&sb[(4 * v1) * 144 + 4 * u1], wr, bv, a1);
            const bool cok = (u1 >= 1 && u1 <= 32);
#pragma unroll
            for (int i = 0; i < 4; i++) {
                int gi = R0 - 4 + 4 * v1 + i;
                bool ok = cok && ((unsigned)gi < 128u);
#pragma unroll
                for (int j = 0; j < 4; j++) if (!ok) a1[i][j] = 0.f;
            }
        }
        __syncthreads();
#pragma unroll
        for (int i = 0; i < 4; i++)
            *(float4*)&sb[(4 * v0 + 2 + i) * 144 + 4 * u0 + 4] =
                make_float4(a0[i][0], a0[i][1], a0[i][2], a0[i][3]);
        if (has2) {
#pragma unroll
            for (int i = 0; i < 4; i++)
                *(float4*)&sb[(4 * v1 + 2 + i) * 144 + 4 * u1 + 4] =
                    make_float4(a1[i][0], a1[i][1], a1[i][2], a1[i][3]);
        }
        __syncthreads();
    }

    // maxpool rows R0..R0+63 (buffer rows 6..69) -> t2: 32x64, float4/thread.
    {
        const int mr = tid >> 4;           // 0..31 pooled row
        const int k2 = tid & 15;           // float4 index 0..15
        const float* p0 = &sb[(6 + 2 * mr) * 144 + 8 + 8 * k2];
        const float* p1 = p0 + 144;
        float4 A = *(const float4*)p0;
        float4 B = *(const float4*)(p0 + 4);
        float4 C = *(const float4*)p1;
        float4 D = *(const float4*)(p1 + 4);
        float4 o;
        o.x = fmaxf(fmaxf(A.x, A.y), fmaxf(C.x, C.y));
        o.y = fmaxf(fmaxf(A.z, A.w), fmaxf(C.z, C.w));
        o.z = fmaxf(fmaxf(B.x, B.y), fmaxf(D.x, D.y));
        o.w = fmaxf(fmaxf(B.z, B.w), fmaxf(D.z, D.w));
        *(float4*)&t2[((size_t)plane * 64 + by * 32 + mr) * 64 + 4 * k2] = o;
    }
}

// ---------------------------------------------------------------------------
// Stage B: per-plane 3x dwconv(64^2) + mean on t2. LDS 68x72 (19.6 KB),
// in place, 512 threads, 2x4 tiles (32x16 grid exact). conv3 -> mean fused.
// ---------------------------------------------------------------------------
__global__ __launch_bounds__(512, 4) void k_b(
    const float* __restrict__ t2, const float* __restrict__ w2,
    const float* __restrict__ b2, float* __restrict__ g)
{
    const int plane = blockIdx.x;
    const int c = plane & 63;
    const int tid = threadIdx.x;

    __shared__ __align__(16) float sb[68 * 72];
    __shared__ float red[8];

    const float* tp = t2 + (size_t)plane * 4096;

    // fill: 68 rows x 18 float4 = 1224 items; interior = image, border zero.
#pragma unroll
    for (int k = 0; k < 3; k++) {
        int i = tid + k * 512;
        if (i < 68 * 18) {
            int r = i / 18, q = i % 18;
            float4 v = make_float4(0.f, 0.f, 0.f, 0.f);
            if (r >= 2 && r < 66 && q >= 1 && q <= 16)
                v = *(const float4*)(tp + (size_t)(r - 2) * 64 + 4 * (q - 1));
            *(float4*)&sb[r * 72 + 4 * q] = v;
        }
    }
    __syncthreads();

    const int v = tid >> 4, u = tid & 15;          // 32 row-tiles x 16 col-tiles
    const float* rb = &sb[(2 * v) * 72 + 4 * u];   // read base
    float* wb = &sb[(2 * v + 2) * 72 + 4 * u + 4]; // write base

#pragma unroll
    for (int cv = 0; cv < 2; cv++) {
        float wr[25];
#pragma unroll
        for (int k = 0; k < 25; k++) wr[k] = w2[cv * CC * 25 + c * 25 + k];
        float a[2][4];
        conv2x4_e12<72>(rb, wr, b2[cv * CC + c], a);
        __syncthreads();
#pragma unroll
        for (int i = 0; i < 2; i++)
            *(float4*)(wb + i * 72) = make_float4(a[i][0], a[i][1], a[i][2], a[i][3]);
        __syncthreads();
    }

    // conv3 feeds mean directly
    float s;
    {
        float wr[25];
#pragma unroll
        for (int k = 0; k < 25; k++) wr[k] = w2[2 * CC * 25 + c * 25 + k];
        float a[2][4];
        conv2x4_e12<72>(rb, wr, b2[2 * CC + c], a);
        s = (a[0][0] + a[0][1] + a[0][2] + a[0][3]) +
            (a[1][0] + a[1][1] + a[1][2] + a[1][3]);
    }
#pragma unroll
    for (int off = 32; off > 0; off >>= 1) s += __shfl_down(s, off);
    if ((tid & 63) == 0) red[tid >> 6] = s;
    __syncthreads();
    if (tid == 0) {
        float t = 0.f;
#pragma unroll
        for (int k = 0; k < 8; k++) t += red[k];
        g[plane] = t * (1.f / 4096.f);
    }
}

// ---------------------------------------------------------------------------
// Kernel 3: kern[o_global] = dot(g[b,:], wk[o,:]) + bk[o];  50*256 = 12800
// ---------------------------------------------------------------------------
__global__ __launch_bounds__(256) void k_kern(
    const float* __restrict__ g, const float* __restrict__ wk,
    const float* __restrict__ bk, float* __restrict__ kern)
{
    const int o = blockIdx.x * 256 + threadIdx.x;     // 0..12799
    const int b = o / 1600, oo = o - b * 1600;
    float v = bk[oo];
    const float* wp = wk + (size_t)oo * 64;
    const float* gp = g + b * 64;
#pragma unroll 16
    for (int k = 0; k < 64; k++) v += gp[k] * wp[k];
    kern[o] = v;
}

// ---------------------------------------------------------------------------
// Kernel 4: dynamic depthwise conv 5x5, 64x64 tile, 4x4 outputs/thread.
// ---------------------------------------------------------------------------
__global__ __launch_bounds__(256) void k_dyn(
    const float* __restrict__ x, const float* __restrict__ kern,
    const float* __restrict__ bias, float* __restrict__ out)
{
    const int plane = blockIdx.z;          // b*64 + c
    const int tx = blockIdx.x, ty = blockIdx.y;   // 4x4 tiles of 64x64
    const int tid = threadIdx.x;

    __shared__ __align__(16) float sx[68 * 76];

    const float* xp = x + (size_t)plane * HH * WW;
    const int R0 = ty * 64, C0 = tx * 64;

    // fill: 68 rows x 18 float4 = 1224 items
#pragma unroll
    for (int k = 0; k < 5; k++) {
        int i = tid + k * 256;
        if (i < 68 * 18) {
            int r = i / 18, q = i - r * 18;
            int gr = R0 - 2 + r;
            int gc = C0 - 4 + 4 * q;
            float4 v = make_float4(0.f, 0.f, 0.f, 0.f);
            if ((unsigned)gr < HH && (unsigned)gc < WW)
                v = *(const float4*)(xp + (size_t)gr * WW + gc);
            *(float4*)&sx[r * 76 + 4 * q] = v;
        }
    }

    float w[25];
#pragma unroll
    for (int k = 0; k < 25; k++) w[k] = kern[(size_t)plane * 25 + k];   // uniform
    const float bv = bias[plane & 63];

    __syncthreads();

    const int tr = (tid >> 4) * 4;      // output row base 0..60
    const int tc = (tid & 15) * 4;      // output col base 0..60
    float acc[4][4];
#pragma unroll
    for (int i = 0; i < 4; i++)
#pragma unroll
        for (int j = 0; j < 4; j++) acc[i][j] = bv;

#pragma unroll
    for (int ir = 0; ir < 8; ir++) {
        const float* s = &sx[(tr + ir) * 76 + tc];
        float4 A = *(const float4*)s;
        float4 B4 = *(const float4*)(s + 4);
        float4 Cv = *(const float4*)(s + 8);
        float e[12] = {A.x, A.y, A.z, A.w, B4.x, B4.y, B4.z, B4.w,
                       Cv.x, Cv.y, Cv.z, Cv.w};
#pragma unroll
        for (int i = 0; i < 4; i++) {
            const int ky = ir - i;
            if (ky >= 0 && ky < 5) {
#pragma unroll
                for (int kx = 0; kx < 5; kx++) {
                    const float wv = w[ky * 5 + kx];
#pragma unroll
                    for (int j = 0; j < 4; j++) acc[i][j] += e[j + kx + 2] * wv;
                }
            }
        }
    }

    float* op = out + (size_t)plane * HH * WW + (size_t)(R0 + tr) * WW + C0 + tc;
#pragma unroll
    for (int i = 0; i < 4; i++)
        *(float4*)(op + (size_t)i * WW) = make_float4(acc[i][0], acc[i][1], acc[i][2], acc[i][3]);
}

// ---------------------------------------------------------------------------
extern "C" void kernel_launch(void* const* d_in, const int* in_sizes, int n_in,
                              void* d_out, int out_size, void* d_ws, size_t ws_size,
                              hipStream_t stream)
{
    const float* x    = (const float*)d_in[0];
    const float* w1   = (const float*)d_in[1];
    const float* b1   = (const float*)d_in[2];
    const float* w2   = (const float*)d_in[3];
    const float* b2   = (const float*)d_in[4];
    const float* wk   = (const float*)d_in[5];
    const float* bk   = (const float*)d_in[6];
    const float* bias = (const float*)d_in[7];
    float* out = (float*)d_out;

    float* ws   = (float*)d_ws;
    float* t2   = ws;                       // 512*64*64 = 2097152 floats
    float* g    = ws + 2097152;             // 512 floats
    float* kern = g + 512;                  // 12800 floats

    k_a1<<<dim3(512, 2), 512, 0, stream>>>(x, w1, b1, t2);
    k_b<<<dim3(512), 512, 0, stream>>>(t2, w2, b2, g);
    k_kern<<<dim3(50), 256, 0, stream>>>(g, wk, bk, kern);
    k_dyn<<<dim3(4, 4, 512), 256, 0, stream>>>(x, kern, bias, out);
}

// Round 9
// 129.491 us; speedup vs baseline: 2.0387x; 2.0387x over previous
//
#include <hip/hip_runtime.h>

#define BB 8
#define CC 64
#define HH 256
#define WW 256
#define KK 5

// 4x4 output block, read-base-relative: reads 8 rows x 3 aligned float4 at
// src + ir*SS; output (i,j) corresponds to src + (2+i)*SS + 4 + j. Taps e[2+j+kx].
template<int SS>
__device__ __forceinline__ void conv4x4_e12(const float* __restrict__ src,
                                            const float* __restrict__ wr,
                                            float bv, float a[4][4])
{
#pragma unroll
    for (int i = 0; i < 4; i++)
#pragma unroll
        for (int j = 0; j < 4; j++) a[i][j] = bv;
#pragma unroll
    for (int ir = 0; ir < 8; ir++) {
        const float* s = src + ir * SS;
        float4 A = *(const float4*)s;
        float4 B = *(const float4*)(s + 4);
        float4 C = *(const float4*)(s + 8);
        float e[12] = {A.x, A.y, A.z, A.w, B.x, B.y, B.z, B.w, C.x, C.y, C.z, C.w};
#pragma unroll
        for (int i = 0; i < 4; i++) {
            const int ky = ir - i;
            if (ky >= 0 && ky < 5) {
#pragma unroll
                for (int kx = 0; kx < 5; kx++) {
                    const float wv = wr[ky * 5 + kx];
#pragma unroll
                    for (int j = 0; j < 4; j++) a[i][j] += e[2 + j + kx] * wv;
                }
            }
        }
    }
}

// 2x4 variant: 6 rows x 3 float4; outputs at src + (2+i)*SS + 4 + j.
template<int SS>
__device__ __forceinline__ void conv2x4_e12(const float* __restrict__ src,
                                            const float* __restrict__ wr,
                                            float bv, float a[2][4])
{
#pragma unroll
    for (int i = 0; i < 2; i++)
#pragma unroll
        for (int j = 0; j < 4; j++) a[i][j] = bv;
#pragma unroll
    for (int ir = 0; ir < 6; ir++) {
        const float* s = src + ir * SS;
        float4 A = *(const float4*)s;
        float4 B = *(const float4*)(s + 4);
        float4 C = *(const float4*)(s + 8);
        float e[12] = {A.x, A.y, A.z, A.w, B.x, B.y, B.z, B.w, C.x, C.y, C.z, C.w};
#pragma unroll
        for (int i = 0; i < 2; i++) {
            const int ky = ir - i;
            if (ky >= 0 && ky < 5) {
#pragma unroll
                for (int kx = 0; kx < 5; kx++) {
                    const float wv = wr[ky * 5 + kx];
#pragma unroll
                    for (int j = 0; j < 4; j++) a[i][j] += e[2 + j + kx] * wv;
                }
            }
        }
    }
}

// ---------------------------------------------------------------------------
// Stage A: avgpool + 3x dwconv(128^2) + maxpool, HALF-plane per block.
// 640 threads, ONE 4x4 tile per thread per conv (no spill). LDS 76x160
// (48.6 KB -> 3 blocks/CU, 30 waves). Stride 160 == 0 mod 32 -> <=2-way banks.
// Layout: buffer row r = pooled image row R0-6+r; image col j at dword 8+j;
// dwords 0..7 / 136..143 are zero margins (cols -8..-5, 132..135).
// Conv tile (v,u): reads rows base..base+7, dwords 4u..4u+11; output rows
// base+2+i, dwords 4u+4+3, i.e. image cols 4u-4..4u-1 (u=0,33 -> margin=0).
// conv3 never writes LDS: its 4x4 tile is reduced 2x2 -> t2 directly.
// ---------------------------------------------------------------------------
__global__ __launch_bounds__(640, 8) void k_a1(
    const float* __restrict__ x, const float* __restrict__ w1,
    const float* __restrict__ b1, float* __restrict__ t2)
{
    const int plane = blockIdx.x;          // b*64 + c
    const int c = plane & 63;
    const int by = blockIdx.y;             // 0,1
    const int R0 = by * 64;                // first image row of this half
    const int tid = threadIdx.x;

    __shared__ __align__(16) float sb[76 * 160];

    const float* xp = x + (size_t)plane * HH * WW;

    // fill: avgpool into buffer. 76 rows x 36 float4 items = 2736.
#pragma unroll
    for (int k = 0; k < 5; k++) {
        int i = tid + k * 640;
        if (i < 76 * 36) {
            int r = i / 36, q = i % 36;
            int pr = R0 - 6 + r;           // pooled row
            float4 v = make_float4(0.f, 0.f, 0.f, 0.f);
            if (q >= 2 && q <= 33 && (unsigned)pr < 128u) {
                int xc = 8 * q - 16;       // x col of first of 8
                const float* p0 = xp + (size_t)(2 * pr) * WW + xc;
                const float* p1 = p0 + WW;
                float4 a0 = *(const float4*)p0;
                float4 a1 = *(const float4*)(p0 + 4);
                float4 b0 = *(const float4*)p1;
                float4 b1v = *(const float4*)(p1 + 4);
                v.x = 0.25f * (a0.x + a0.y + b0.x + b0.y);
                v.y = 0.25f * (a0.z + a0.w + b0.z + b0.w);
                v.z = 0.25f * (a1.x + a1.y + b1v.x + b1v.y);
                v.w = 0.25f * (a1.z + a1.w + b1v.z + b1v.w);
            }
            *(float4*)&sb[r * 160 + 4 * q] = v;
        }
    }
    __syncthreads();

    const int v = tid / 34, u = tid % 34;

    // conv1: 18x34 = 612 tiles. out image rows R0-4+4v+i (buffer 2+4v+i).
    {
        float wr[25];
#pragma unroll
        for (int k = 0; k < 25; k++) wr[k] = w1[0 * CC * 25 + c * 25 + k];
        const float bv = b1[0 * CC + c];
        float a[4][4];
        const bool act = tid < 612;
        if (act) {
            conv4x4_e12<160>(&sb[(4 * v) * 160 + 4 * u], wr, bv, a);
            const bool cok = (u >= 1 && u <= 32);
#pragma unroll
            for (int i = 0; i < 4; i++) {
                int gi = R0 - 4 + 4 * v + i;
                bool ok = cok && ((unsigned)gi < 128u);
#pragma unroll
                for (int j = 0; j < 4; j++) if (!ok) a[i][j] = 0.f;
            }
        }
        __syncthreads();
        if (act) {
#pragma unroll
            for (int i = 0; i < 4; i++)
                *(float4*)&sb[(4 * v + 2 + i) * 160 + 4 * u + 4] =
                    make_float4(a[i][0], a[i][1], a[i][2], a[i][3]);
        }
        __syncthreads();
    }

    // conv2: 17x34 = 578 tiles. out image rows R0-2+4v+i (buffer 4+4v+i).
    {
        float wr[25];
#pragma unroll
        for (int k = 0; k < 25; k++) wr[k] = w1[1 * CC * 25 + c * 25 + k];
        const float bv = b1[1 * CC + c];
        float a[4][4];
        const bool act = tid < 578;
        if (act) {
            conv4x4_e12<160>(&sb[(2 + 4 * v) * 160 + 4 * u], wr, bv, a);
            const bool cok = (u >= 1 && u <= 32);
#pragma unroll
            for (int i = 0; i < 4; i++) {
                int gi = R0 - 2 + 4 * v + i;
                bool ok = cok && ((unsigned)gi < 128u);
#pragma unroll
                for (int j = 0; j < 4; j++) if (!ok) a[i][j] = 0.f;
            }
        }
        __syncthreads();
        if (act) {
#pragma unroll
            for (int i = 0; i < 4; i++)
                *(float4*)&sb[(4 + 4 * v + i) * 160 + 4 * u + 4] =
                    make_float4(a[i][0], a[i][1], a[i][2], a[i][3]);
        }
        __syncthreads();
    }

    // conv3 + maxpool fused: 16x34 = 544 tiles, out rows R0+4v+i (always in
    // image). 2x2 max of the 4x4 tile -> t2 (float2 stores), cols u in [1,32].
    {
        float wr[25];
#pragma unroll
        for (int k = 0; k < 25; k++) wr[k] = w1[2 * CC * 25 + c * 25 + k];
        const float bv = b1[2 * CC + c];
        if (tid < 544) {
            float a[4][4];
            conv4x4_e12<160>(&sb[(4 + 4 * v) * 160 + 4 * u], wr, bv, a);
            if (u >= 1 && u <= 32) {
                const int pr0 = (R0 >> 1) + 2 * v;     // pooled row base
                const int pc0 = 2 * u - 2;             // pooled col base
#pragma unroll
                for (int ii = 0; ii < 2; ii++) {
                    float m0 = fmaxf(fmaxf(a[2 * ii][0], a[2 * ii][1]),
                                     fmaxf(a[2 * ii + 1][0], a[2 * ii + 1][1]));
                    float m1 = fmaxf(fmaxf(a[2 * ii][2], a[2 * ii][3]),
                                     fmaxf(a[2 * ii + 1][2], a[2 * ii + 1][3]));
                    *(float2*)&t2[((size_t)plane * 64 + pr0 + ii) * 64 + pc0] =
                        make_float2(m0, m1);
                }
            }
        }
    }
}

// ---------------------------------------------------------------------------
// Stage B: per-plane 3x dwconv(64^2) + mean on t2. LDS 68x72 (19.6 KB),
// in place, 512 threads, 2x4 tiles (32x16 grid exact). conv3 -> mean fused.
// ---------------------------------------------------------------------------
__global__ __launch_bounds__(512, 4) void k_b(
    const float* __restrict__ t2, const float* __restrict__ w2,
    const float* __restrict__ b2, float* __restrict__ g)
{
    const int plane = blockIdx.x;
    const int c = plane & 63;
    const int tid = threadIdx.x;

    __shared__ __align__(16) float sb[68 * 72];
    __shared__ float red[8];

    const float* tp = t2 + (size_t)plane * 4096;

    // fill: 68 rows x 18 float4 = 1224 items; interior = image, border zero.
#pragma unroll
    for (int k = 0; k < 3; k++) {
        int i = tid + k * 512;
        if (i < 68 * 18) {
            int r = i / 18, q = i % 18;
            float4 v = make_float4(0.f, 0.f, 0.f, 0.f);
            if (r >= 2 && r < 66 && q >= 1 && q <= 16)
                v = *(const float4*)(tp + (size_t)(r - 2) * 64 + 4 * (q - 1));
            *(float4*)&sb[r * 72 + 4 * q] = v;
        }
    }
    __syncthreads();

    const int v = tid >> 4, u = tid & 15;          // 32 row-tiles x 16 col-tiles
    const float* rb = &sb[(2 * v) * 72 + 4 * u];   // read base
    float* wb = &sb[(2 * v + 2) * 72 + 4 * u + 4]; // write base

#pragma unroll
    for (int cv = 0; cv < 2; cv++) {
        float wr[25];
#pragma unroll
        for (int k = 0; k < 25; k++) wr[k] = w2[cv * CC * 25 + c * 25 + k];
        float a[2][4];
        conv2x4_e12<72>(rb, wr, b2[cv * CC + c], a);
        __syncthreads();
#pragma unroll
        for (int i = 0; i < 2; i++)
            *(float4*)(wb + i * 72) = make_float4(a[i][0], a[i][1], a[i][2], a[i][3]);
        __syncthreads();
    }

    // conv3 feeds mean directly
    float s;
    {
        float wr[25];
#pragma unroll
        for (int k = 0; k < 25; k++) wr[k] = w2[2 * CC * 25 + c * 25 + k];
        float a[2][4];
        conv2x4_e12<72>(rb, wr, b2[2 * CC + c], a);
        s = (a[0][0] + a[0][1] + a[0][2] + a[0][3]) +
            (a[1][0] + a[1][1] + a[1][2] + a[1][3]);
    }
#pragma unroll
    for (int off = 32; off > 0; off >>= 1) s += __shfl_down(s, off);
    if ((tid & 63) == 0) red[tid >> 6] = s;
    __syncthreads();
    if (tid == 0) {
        float t = 0.f;
#pragma unroll
        for (int k = 0; k < 8; k++) t += red[k];
        g[plane] = t * (1.f / 4096.f);
    }
}

// ---------------------------------------------------------------------------
// Kernel 3: kern[o_global] = dot(g[b,:], wk[o,:]) + bk[o];  50*256 = 12800
// ---------------------------------------------------------------------------
__global__ __launch_bounds__(256) void k_kern(
    const float* __restrict__ g, const float* __restrict__ wk,
    const float* __restrict__ bk, float* __restrict__ kern)
{
    const int o = blockIdx.x * 256 + threadIdx.x;     // 0..12799
    const int b = o / 1600, oo = o - b * 1600;
    float v = bk[oo];
    const float* wp = wk + (size_t)oo * 64;
    const float* gp = g + b * 64;
#pragma unroll 16
    for (int k = 0; k < 64; k++) v += gp[k] * wp[k];
    kern[o] = v;
}

// ---------------------------------------------------------------------------
// Kernel 4: dynamic depthwise conv 5x5, 64x64 tile, 4x4 outputs/thread.
// ---------------------------------------------------------------------------
__global__ __launch_bounds__(256) void k_dyn(
    const float* __restrict__ x, const float* __restrict__ kern,
    const float* __restrict__ bias, float* __restrict__ out)
{
    const int plane = blockIdx.z;          // b*64 + c
    const int tx = blockIdx.x, ty = blockIdx.y;   // 4x4 tiles of 64x64
    const int tid = threadIdx.x;

    __shared__ __align__(16) float sx[68 * 76];

    const float* xp = x + (size_t)plane * HH * WW;
    const int R0 = ty * 64, C0 = tx * 64;

    // fill: 68 rows x 18 float4 = 1224 items
#pragma unroll
    for (int k = 0; k < 5; k++) {
        int i = tid + k * 256;
        if (i < 68 * 18) {
            int r = i / 18, q = i - r * 18;
            int gr = R0 - 2 + r;
            int gc = C0 - 4 + 4 * q;
            float4 v = make_float4(0.f, 0.f, 0.f, 0.f);
            if ((unsigned)gr < HH && (unsigned)gc < WW)
                v = *(const float4*)(xp + (size_t)gr * WW + gc);
            *(float4*)&sx[r * 76 + 4 * q] = v;
        }
    }

    float w[25];
#pragma unroll
    for (int k = 0; k < 25; k++) w[k] = kern[(size_t)plane * 25 + k];   // uniform
    const float bv = bias[plane & 63];

    __syncthreads();

    const int tr = (tid >> 4) * 4;      // output row base 0..60
    const int tc = (tid & 15) * 4;      // output col base 0..60
    float acc[4][4];
#pragma unroll
    for (int i = 0; i < 4; i++)
#pragma unroll
        for (int j = 0; j < 4; j++) acc[i][j] = bv;

#pragma unroll
    for (int ir = 0; ir < 8; ir++) {
        const float* s = &sx[(tr + ir) * 76 + tc];
        float4 A = *(const float4*)s;
        float4 B4 = *(const float4*)(s + 4);
        float4 Cv = *(const float4*)(s + 8);
        float e[12] = {A.x, A.y, A.z, A.w, B4.x, B4.y, B4.z, B4.w,
                       Cv.x, Cv.y, Cv.z, Cv.w};
#pragma unroll
        for (int i = 0; i < 4; i++) {
            const int ky = ir - i;
            if (ky >= 0 && ky < 5) {
#pragma unroll
                for (int kx = 0; kx < 5; kx++) {
                    const float wv = w[ky * 5 + kx];
#pragma unroll
                    for (int j = 0; j < 4; j++) acc[i][j] += e[j + kx + 2] * wv;
                }
            }
        }
    }

    float* op = out + (size_t)plane * HH * WW + (size_t)(R0 + tr) * WW + C0 + tc;
#pragma unroll
    for (int i = 0; i < 4; i++)
        *(float4*)(op + (size_t)i * WW) = make_float4(acc[i][0], acc[i][1], acc[i][2], acc[i][3]);
}

// ---------------------------------------------------------------------------
extern "C" void kernel_launch(void* const* d_in, const int* in_sizes, int n_in,
                              void* d_out, int out_size, void* d_ws, size_t ws_size,
                              hipStream_t stream)
{
    const float* x    = (const float*)d_in[0];
    const float* w1   = (const float*)d_in[1];
    const float* b1   = (const float*)d_in[2];
    const float* w2   = (const float*)d_in[3];
    const float* b2   = (const float*)d_in[4];
    const float* wk   = (const float*)d_in[5];
    const float* bk   = (const float*)d_in[6];
    const float* bias = (const float*)d_in[7];
    float* out = (float*)d_out;

    float* ws   = (float*)d_ws;
    float* t2   = ws;                       // 512*64*64 = 2097152 floats
    float* g    = ws + 2097152;             // 512 floats
    float* kern = g + 512;                  // 12800 floats

    k_a1<<<dim3(512, 2), 640, 0, stream>>>(x, w1, b1, t2);
    k_b<<<dim3(512), 512, 0, stream>>>(t2, w2, b2, g);
    k_kern<<<dim3(50), 256, 0, stream>>>(g, wk, bk, kern);
    k_dyn<<<dim3(4, 4, 512), 256, 0, stream>>>(x, kern, bias, out);
}